// Round 5
// baseline (43.046 us; speedup 1.0000x reference)
//
#include <hip/hip_runtime.h>
#include <hip/hip_bf16.h>

#define OUT_N 8192
#define IN_N  8192
#define QROW  (IN_N / 2)         // 4096 int32 per out row (one widened byte each)
#define WAVES 8
#define CH_I32 512               // int32 per row per chunk (= 1024 in-elems)
#define NCHUNK (QROW / CH_I32)   // 8
#define STEPS 4                  // mfma k-steps per wave per chunk (128 elems/32)

typedef __attribute__((ext_vector_type(8))) short short8v;  // 8 bf16
typedef __attribute__((ext_vector_type(4))) float f32x4;

__device__ __forceinline__ unsigned int bf16pk(float a, float b) {
    __hip_bfloat162 h = __float22bfloat162_rn(make_float2(a, b));
    unsigned int u;
    __builtin_memcpy(&u, &h, 4);
    return u;
}

// async global->LDS, 16B per lane; LDS dest = wave-uniform base + lane*16 (HW)
__device__ __forceinline__ void gld_lds16(const int* gsrc, int* ldst_base) {
    __builtin_amdgcn_global_load_lds(
        (const __attribute__((address_space(1))) void*)gsrc,
        (__attribute__((address_space(3))) void*)ldst_base, 16, 0, 0);
}

// Pre-pass: x fp32 -> bf16 row-major [16][8192] in d_ws (256 KB, L2/L3-hot).
__global__ __launch_bounds__(256) void xconv_kernel(
    const float* __restrict__ x, unsigned short* __restrict__ xb)
{
    int i = (blockIdx.x * 256 + threadIdx.x) * 4;
    float4 v = *(const float4*)(x + i);
    uint2 u = { bf16pk(v.x, v.y), bf16pk(v.z, v.w) };
    *(uint2*)(xb + i) = u;
}

// One block = one 16-out-row tile. q staged into LDS double-buffer with fully
// contiguous 1KB-per-wave global_load_lds DMA (wave w stages rows 2w,2w+1);
// 8 waves split each chunk's K 8 ways for the MFMA. One barrier per chunk:
// the vmcnt drain at __syncthreads doubles as the DMA-completion fence.
__global__ __launch_bounds__(512) void qlin_mfma_kernel(
    const int*            __restrict__ qp,
    const unsigned short* __restrict__ xb,
    const float*          __restrict__ scale,
    const float*          __restrict__ bias,
    float*                __restrict__ out)
{
    __shared__ int buf[2][16][CH_I32];    // 64 KB

    const int t = threadIdx.x;
    const int w = t >> 6;           // wave id
    const int l = t & 63;
    const int g = l >> 4;           // lane group 0..3 (k sub-offset)
    const int r = l & 15;           // A: batch row, B: out row within tile
    const int tile = blockIdx.x;

    const int R0 = 2 * w;                          // rows this wave stages
    const int* qrow0 = qp + (size_t)(tile * 16 + R0) * QROW;
    const int* qrow1 = qrow0 + QROW;

    f32x4 acc = {0.f, 0.f, 0.f, 0.f};

    // ---- stage chunk 0
    #pragma unroll
    for (int p = 0; p < 2; ++p) {
        gld_lds16(qrow0 + p * 256 + l * 4, &buf[0][R0][p * 256]);
        gld_lds16(qrow1 + p * 256 + l * 4, &buf[0][R0 + 1][p * 256]);
    }
    __syncthreads();   // drain: chunk 0 resident

    for (int c = 0; c < NCHUNK; ++c) {
        const int cur = c & 1;

        // issue next chunk's DMA into the other buffer (read last chunk, free)
        if (c + 1 < NCHUNK) {
            const int nb = c + 1;
            #pragma unroll
            for (int p = 0; p < 2; ++p) {
                gld_lds16(qrow0 + nb * CH_I32 + p * 256 + l * 4, &buf[cur ^ 1][R0][p * 256]);
                gld_lds16(qrow1 + nb * CH_I32 + p * 256 + l * 4, &buf[cur ^ 1][R0 + 1][p * 256]);
            }
        }

        // x fragments for this chunk (L2/L3-hot, 4 x dwordx4)
        uint4 xa[STEPS];
        #pragma unroll
        for (int s = 0; s < STEPS; ++s)
            xa[s] = *(const uint4*)(xb + (size_t)r * IN_N + c * 1024 + w * 128 + s * 32 + g * 8);

        // compute this chunk: wave w covers int32 [w*64, w*64+64) of the chunk
        #pragma unroll
        for (int s = 0; s < STEPS; ++s) {
            const int4 q = *(const int4*)&buf[cur][r][w * 64 + s * 16 + g * 4];
            // nibble e=2m lo / e=2m+1 hi of byte m; signed; exact in bf16
            uint4 ub = {
                bf16pk((float)((q.x << 28) >> 28), (float)((q.x << 24) >> 28)),
                bf16pk((float)((q.y << 28) >> 28), (float)((q.y << 24) >> 28)),
                bf16pk((float)((q.z << 28) >> 28), (float)((q.z << 24) >> 28)),
                bf16pk((float)((q.w << 28) >> 28), (float)((q.w << 24) >> 28))
            };
            short8v bfrag = __builtin_bit_cast(short8v, ub);
            short8v afrag = __builtin_bit_cast(short8v, xa[s]);
            acc = __builtin_amdgcn_mfma_f32_16x16x32_bf16(afrag, bfrag, acc, 0, 0, 0);
        }

        __syncthreads();  // all reads of buf[cur] done; own DMA for c+1 drained
    }

    // ---- cross-wave K reduction; reuse buf as scratch (last barrier passed)
    float (*red)[16][17] = (float (*)[16][17])buf;   // 8*16*17*4 B < 64 KB
    red[w][g * 4 + 0][r] = acc[0];
    red[w][g * 4 + 1][r] = acc[1];
    red[w][g * 4 + 2][r] = acc[2];
    red[w][g * 4 + 3][r] = acc[3];
    __syncthreads();

    if (t < 256) {
        const int b = t >> 4;           // batch
        const int o = t & 15;           // out within tile
        const int oc = tile * 16 + o;
        float v = 0.f;
        #pragma unroll
        for (int i = 0; i < WAVES; ++i) v += red[i][b][o];
        out[b * OUT_N + oc] = v * scale[oc >> 7] + bias[oc];
    }
}

extern "C" void kernel_launch(void* const* d_in, const int* in_sizes, int n_in,
                              void* d_out, int out_size, void* d_ws, size_t ws_size,
                              hipStream_t stream) {
    (void)in_sizes; (void)n_in; (void)ws_size; (void)out_size;
    const float* x     = (const float*)d_in[0];
    const int*   qp    = (const int*)d_in[1];
    const float* scale = (const float*)d_in[2];
    const float* bias  = (const float*)d_in[3];
    float*       out   = (float*)d_out;
    unsigned short* xb = (unsigned short*)d_ws;    // 256 KB bf16 x

    xconv_kernel<<<dim3((16 * IN_N) / (256 * 4)), dim3(256), 0, stream>>>(x, xb);
    qlin_mfma_kernel<<<dim3(OUT_N / 16), dim3(512), 0, stream>>>(qp, xb, scale, bias, out);
}

// Round 6
// 32.864 us; speedup vs baseline: 1.3098x; 1.3098x over previous
//
#include <hip/hip_runtime.h>
#include <hip/hip_bf16.h>

#define OUT_N 8192
#define IN_N  8192
#define QROW  (IN_N / 2)     // 4096 int32 per out row (one widened byte each)
#define NCH   8              // k sub-chunks per wave
#define CH32  64             // int32 per row per sub-chunk (per wave)

typedef __attribute__((ext_vector_type(8))) short short8v;  // 8 bf16
typedef __attribute__((ext_vector_type(4))) float f32x4;

__device__ __forceinline__ unsigned int bf16pk(float a, float b) {
    __hip_bfloat162 h = __float22bfloat162_rn(make_float2(a, b));
    unsigned int u;
    __builtin_memcpy(&u, &h, 4);
    return u;
}

// async global->LDS, 16B/lane; LDS dest = wave-uniform base + lane*16 (HW rule)
__device__ __forceinline__ void gld_lds16(const int* gsrc, int* ldst_base) {
    __builtin_amdgcn_global_load_lds(
        (const __attribute__((address_space(1))) void*)gsrc,
        (__attribute__((address_space(3))) void*)ldst_base, 16, 0, 0);
}

// Pre-pass: x fp32 -> bf16 row-major [16][8192] in d_ws (256 KB, L2/L3-hot).
__global__ __launch_bounds__(256) void xconv_kernel(
    const float* __restrict__ x, unsigned short* __restrict__ xb)
{
    int i = (blockIdx.x * 256 + threadIdx.x) * 4;
    float4 v = *(const float4*)(x + i);
    uint2 u = { bf16pk(v.x, v.y), bf16pk(v.z, v.w) };
    *(uint2*)(xb + i) = u;
}

// One block = one 16-out-row tile; 8 waves split K 8 ways. WAVE-PRIVATE q
// staging: each wave DMAs the exact 4KB slice it consumes (16 rows x 256B of
// its k-range) into its own LDS double buffer -> NO __syncthreads in the main
// loop; counted vmcnt(8) keeps next chunk's 8 vmem ops in flight (T4).
// LDS read swizzle: slot j stored at j^r (global source pre-swizzled, m173).
__global__ __launch_bounds__(512, 4) void qlin_mfma_kernel(
    const int*            __restrict__ qp,
    const unsigned short* __restrict__ xb,
    const float*          __restrict__ scale,
    const float*          __restrict__ bias,
    float*                __restrict__ out)
{
    __shared__ int   qbuf[8][2][16 * CH32];   // 8 waves x 2 x 4KB = 64 KB
    __shared__ float red[8][16][17];          // 8.5 KB reduction scratch

    const int t = threadIdx.x;
    const int w = t >> 6;            // wave id -> k range [w*1024, +1024) elems
    const int l = t & 63;
    const int g = l >> 4;            // lane group 0..3
    const int r = l & 15;            // A: batch row, B: out row within tile
    const int tile = blockIdx.x;
    const int obase = tile * 16;

    // wave-uniform q base for this wave's k-range (int32 units)
    const int* qwbase = qp + (size_t)obase * QROW + w * (QROW / 8);
    // per-lane DMA source row/colslot (pre-swizzled: slot j lands at LDS j^row)
    const int drow = l >> 4;                      // +4p per instr
    // x fragment base (bf16 elems)
    const unsigned short* xwbase = xb + (size_t)r * IN_N + w * (IN_N / 8);

    f32x4 acc = {0.f, 0.f, 0.f, 0.f};
    uint4 xr[2][4];

    // ---- prologue: x loads then DMAs for chunk 0 (8 vmem ops outstanding)
    #pragma unroll
    for (int s = 0; s < 4; ++s)
        xr[0][s] = *(const uint4*)(xwbase + s * 32 + g * 8);
    #pragma unroll
    for (int p = 0; p < 4; ++p) {
        const int row = 4 * p + drow;
        const int j   = (l & 15) ^ (row & 15);
        gld_lds16(qwbase + (size_t)row * QROW + j * 4, &qbuf[w][0][p * 256]);
    }

    #pragma unroll   // full unroll: static buffer indices + static vmcnt imms
    for (int c = 0; c < NCH; ++c) {
        const int cur = c & 1;

        if (c + 1 < NCH) {
            // issue next chunk: x loads FIRST (retire first), then DMAs
            #pragma unroll
            for (int s = 0; s < 4; ++s)
                xr[cur ^ 1][s] = *(const uint4*)(xwbase + (c + 1) * 128 + s * 32 + g * 8);
            #pragma unroll
            for (int p = 0; p < 4; ++p) {
                const int row = 4 * p + drow;
                const int j   = (l & 15) ^ (row & 15);
                gld_lds16(qwbase + (size_t)row * QROW + (c + 1) * CH32 + j * 4,
                          &qbuf[w][cur ^ 1][p * 256]);
            }
            // retire chunk c's 8 ops; leave chunk c+1's 8 in flight
            asm volatile("s_waitcnt vmcnt(8)" ::: "memory");
        } else {
            asm volatile("s_waitcnt vmcnt(0)" ::: "memory");
        }
        __builtin_amdgcn_sched_barrier(0);   // rule #18: pin ds_reads below wait

        const char* wb = (const char*)qbuf[w][cur];
        #pragma unroll
        for (int s = 0; s < 4; ++s) {
            // read slot j0 = s*4+g of row r, stored at slot j0^r (2-way = free)
            const int4 q = *(const int4*)(wb + r * 256 + ((((s << 2) + g) ^ r) << 4));
            // nibble e=2m lo / e=2m+1 hi of byte m; signed; exact in bf16
            uint4 ub = {
                bf16pk((float)((q.x << 28) >> 28), (float)((q.x << 24) >> 28)),
                bf16pk((float)((q.y << 28) >> 28), (float)((q.y << 24) >> 28)),
                bf16pk((float)((q.z << 28) >> 28), (float)((q.z << 24) >> 28)),
                bf16pk((float)((q.w << 28) >> 28), (float)((q.w << 24) >> 28))
            };
            short8v bfrag = __builtin_bit_cast(short8v, ub);
            short8v afrag = __builtin_bit_cast(short8v, xr[cur][s]);
            acc = __builtin_amdgcn_mfma_f32_16x16x32_bf16(afrag, bfrag, acc, 0, 0, 0);
        }
    }

    // ---- cross-wave K reduction; D map: col=lane&15 (out), row=(lane>>4)*4+j
    red[w][g * 4 + 0][r] = acc[0];
    red[w][g * 4 + 1][r] = acc[1];
    red[w][g * 4 + 2][r] = acc[2];
    red[w][g * 4 + 3][r] = acc[3];
    __syncthreads();

    if (t < 256) {
        const int b = t >> 4;            // batch
        const int o = t & 15;            // out within tile
        const int oc = obase + o;
        float v = 0.f;
        #pragma unroll
        for (int i = 0; i < 8; ++i) v += red[i][b][o];
        out[b * OUT_N + oc] = v * scale[oc >> 7] + bias[oc];
    }
}

extern "C" void kernel_launch(void* const* d_in, const int* in_sizes, int n_in,
                              void* d_out, int out_size, void* d_ws, size_t ws_size,
                              hipStream_t stream) {
    (void)in_sizes; (void)n_in; (void)ws_size; (void)out_size;
    const float* x     = (const float*)d_in[0];
    const int*   qp    = (const int*)d_in[1];
    const float* scale = (const float*)d_in[2];
    const float* bias  = (const float*)d_in[3];
    float*       out   = (float*)d_out;
    unsigned short* xb = (unsigned short*)d_ws;    // 256 KB bf16 x

    xconv_kernel<<<dim3((16 * IN_N) / (256 * 4)), dim3(256), 0, stream>>>(x, xb);
    qlin_mfma_kernel<<<dim3(OUT_N / 16), dim3(512), 0, stream>>>(qp, xb, scale, bias, out);
}